// Round 1
// baseline (406.461 us; speedup 1.0000x reference)
//
#include <hip/hip_runtime.h>

#define E_   1024
#define H_   16
#define DK_  64
#define FFN_ 4096
#define NQ_  8
#define B_   2
#define T_   2048
#define QBLK 64
#define KVBLK 64

typedef __attribute__((ext_vector_type(8))) __bf16 bf16x8;
typedef __attribute__((ext_vector_type(4))) float f32x4;

__device__ __forceinline__ __bf16 tobf(float f) { return (__bf16)f; }

// ---------------------------------------------------------------------------
// Kernel 1: constant FFN vector  ffn_c[e] = relu(q_out@w1 + b1) @ w2 + b2
// grid = 16 blocks x 256 thr; block handles 64 output columns
// ---------------------------------------------------------------------------
__global__ __launch_bounds__(256)
void ffn_const_kernel(const float* __restrict__ q_out, const float* __restrict__ w1,
                      const float* __restrict__ b1, const float* __restrict__ w2,
                      const float* __restrict__ b2, float* __restrict__ ffn_c) {
  __shared__ float h[FFN_];
  __shared__ float red[256];
  const int tid = threadIdx.x;
  float q[NQ_];
#pragma unroll
  for (int n = 0; n < NQ_; ++n) q[n] = q_out[n];
  for (int f = tid; f < FFN_; f += 256) {
    float a = b1[f];
#pragma unroll
    for (int n = 0; n < NQ_; ++n) a += q[n] * w1[n * FFN_ + f];
    h[f] = fmaxf(a, 0.f);
  }
  __syncthreads();
  const int col = blockIdx.x * 64 + (tid & 63);
  const int part = tid >> 6;
  float a = 0.f;
  for (int f = part * 1024; f < part * 1024 + 1024; ++f)
    a += h[f] * w2[(size_t)f * E_ + col];
  red[tid] = a;
  __syncthreads();
  if (part == 0)
    ffn_c[col] = red[tid] + red[tid + 64] + red[tid + 128] + red[tid + 192] + b2[col];
}

// ---------------------------------------------------------------------------
// Kernel 2: flash attention, q=k=v = head-split x.  bf16 MFMA, f32 softmax.
// grid = (T/QBLK, B*H), 256 thr = 4 waves, wave owns 16 q-rows.
// ---------------------------------------------------------------------------
__global__ __launch_bounds__(256)
void attn_kernel(const float* __restrict__ x, float* __restrict__ out) {
  __shared__ __bf16 Kl[KVBLK][DK_ + 8];       // K-tile row-major [key][d]
  __shared__ __bf16 Vt[DK_][KVBLK + 8];       // V-tile transposed [d][key]
  __shared__ __bf16 Pl[4][16][KVBLK + 8];     // per-wave P tile [qrow][key]

  const int tid  = threadIdx.x;
  const int wave = tid >> 6;
  const int lane = tid & 63;
  const int l16  = lane & 15;
  const int lhi  = lane >> 4;          // 0..3

  const int bh = blockIdx.y;
  const int b  = bh >> 4;              // / H
  const int h  = bh & 15;
  const int qbase = blockIdx.x * QBLK;
  const float* xb = x + (size_t)b * T_ * E_ + h * DK_;   // row stride E_

  // Q fragments for this wave's 16 rows (A-layout: row = l16, k = lhi*8+i)
  bf16x8 qa[2];
  {
    const float* qrow = xb + (size_t)(qbase + wave * 16 + l16) * E_;
#pragma unroll
    for (int kk = 0; kk < 2; ++kk) {
      const float4* p = reinterpret_cast<const float4*>(qrow + kk * 32 + lhi * 8);
      float4 u0 = p[0], u1 = p[1];
      bf16x8 v;
      v[0] = tobf(u0.x); v[1] = tobf(u0.y); v[2] = tobf(u0.z); v[3] = tobf(u0.w);
      v[4] = tobf(u1.x); v[5] = tobf(u1.y); v[6] = tobf(u1.z); v[7] = tobf(u1.w);
      qa[kk] = v;
    }
  }

  f32x4 acc[4];
#pragma unroll
  for (int i = 0; i < 4; ++i) acc[i] = (f32x4){0.f, 0.f, 0.f, 0.f};
  float m_i[4] = {-1e30f, -1e30f, -1e30f, -1e30f};
  float l_i[4] = {0.f, 0.f, 0.f, 0.f};

  const int key = tid >> 2;            // 0..63
  const int d0  = (tid & 3) * 16;      // 0,16,32,48

  for (int t = 0; t < T_ / KVBLK; ++t) {
    __syncthreads();   // all waves done reading K/Vt of previous tile
    // ---- stage K-tile (row-major) and V-tile (transposed) ----
    {
      const float* src = xb + (size_t)(t * KVBLK + key) * E_ + d0;
      const float4* sp = reinterpret_cast<const float4*>(src);
      float4 a0 = sp[0], a1 = sp[1], a2 = sp[2], a3 = sp[3];
      __bf16 tmp[16];
      tmp[0] = tobf(a0.x); tmp[1] = tobf(a0.y); tmp[2] = tobf(a0.z); tmp[3] = tobf(a0.w);
      tmp[4] = tobf(a1.x); tmp[5] = tobf(a1.y); tmp[6] = tobf(a1.z); tmp[7] = tobf(a1.w);
      tmp[8] = tobf(a2.x); tmp[9] = tobf(a2.y); tmp[10] = tobf(a2.z); tmp[11] = tobf(a2.w);
      tmp[12] = tobf(a3.x); tmp[13] = tobf(a3.y); tmp[14] = tobf(a3.z); tmp[15] = tobf(a3.w);
      bf16x8 v0, v1;
#pragma unroll
      for (int j = 0; j < 8; ++j) { v0[j] = tmp[j]; v1[j] = tmp[8 + j]; }
      bf16x8* krow = reinterpret_cast<bf16x8*>(&Kl[key][d0]);
      krow[0] = v0; krow[1] = v1;
#pragma unroll
      for (int j = 0; j < 16; ++j) Vt[d0 + j][key] = tmp[j];
    }
    __syncthreads();

    // ---- S = Q K^T / 8 ----
    f32x4 s[4];
#pragma unroll
    for (int tn = 0; tn < 4; ++tn) {
      bf16x8 kb0 = *reinterpret_cast<const bf16x8*>(&Kl[tn * 16 + l16][lhi * 8]);
      bf16x8 kb1 = *reinterpret_cast<const bf16x8*>(&Kl[tn * 16 + l16][32 + lhi * 8]);
      f32x4 c = (f32x4){0.f, 0.f, 0.f, 0.f};
      c = __builtin_amdgcn_mfma_f32_16x16x32_bf16(qa[0], kb0, c, 0, 0, 0);
      c = __builtin_amdgcn_mfma_f32_16x16x32_bf16(qa[1], kb1, c, 0, 0, 0);
      s[tn] = c * 0.125f;
    }

    // ---- online softmax (rows = lhi*4+i) ----
#pragma unroll
    for (int i = 0; i < 4; ++i) {
      float rm = fmaxf(fmaxf(s[0][i], s[1][i]), fmaxf(s[2][i], s[3][i]));
#pragma unroll
      for (int off = 1; off < 16; off <<= 1) rm = fmaxf(rm, __shfl_xor(rm, off));
      float mn = fmaxf(m_i[i], rm);
      float corr = __expf(m_i[i] - mn);
      m_i[i] = mn;
      float rs = 0.f;
#pragma unroll
      for (int tn = 0; tn < 4; ++tn) {
        float p = __expf(s[tn][i] - mn);
        s[tn][i] = p;
        rs += p;
      }
#pragma unroll
      for (int off = 1; off < 16; off <<= 1) rs += __shfl_xor(rs, off);
      l_i[i] = l_i[i] * corr + rs;
#pragma unroll
      for (int td = 0; td < 4; ++td) acc[td][i] *= corr;
#pragma unroll
      for (int tn = 0; tn < 4; ++tn)
        Pl[wave][lhi * 4 + i][tn * 16 + l16] = tobf(s[tn][i]);
    }
    asm volatile("s_waitcnt lgkmcnt(0)" ::: "memory");  // P writes visible wave-wide

    // ---- O += P V ----
    bf16x8 pa0 = *reinterpret_cast<const bf16x8*>(&Pl[wave][l16][lhi * 8]);
    bf16x8 pa1 = *reinterpret_cast<const bf16x8*>(&Pl[wave][l16][32 + lhi * 8]);
#pragma unroll
    for (int td = 0; td < 4; ++td) {
      bf16x8 vb0 = *reinterpret_cast<const bf16x8*>(&Vt[td * 16 + l16][lhi * 8]);
      bf16x8 vb1 = *reinterpret_cast<const bf16x8*>(&Vt[td * 16 + l16][32 + lhi * 8]);
      acc[td] = __builtin_amdgcn_mfma_f32_16x16x32_bf16(pa0, vb0, acc[td], 0, 0, 0);
      acc[td] = __builtin_amdgcn_mfma_f32_16x16x32_bf16(pa1, vb1, acc[td], 0, 0, 0);
    }
  }

  // ---- epilogue: O / l -> out (attn staged in d_out) ----
#pragma unroll
  for (int td = 0; td < 4; ++td)
#pragma unroll
    for (int i = 0; i < 4; ++i) {
      const int tq  = qbase + wave * 16 + lhi * 4 + i;
      const int col = h * DK_ + td * 16 + l16;
      out[((size_t)b * T_ + tq) * E_ + col] = acc[td][i] / l_i[i];
    }
}

// ---------------------------------------------------------------------------
// Kernel 3: out = LN2( LN1(x + attn) + ffn_c ), in-place on d_out (attn).
// grid = B*T rows, 256 thr, 4 f32/thread.
// ---------------------------------------------------------------------------
__device__ __forceinline__ float block_sum(float v, float* redrow, int lane, int wave) {
#pragma unroll
  for (int off = 1; off < 64; off <<= 1) v += __shfl_xor(v, off);
  if (lane == 0) redrow[wave] = v;
  __syncthreads();
  return redrow[0] + redrow[1] + redrow[2] + redrow[3];
}

__global__ __launch_bounds__(256)
void ln_kernel(const float* __restrict__ x, const float* __restrict__ ffn_c,
               const float* __restrict__ g1, const float* __restrict__ be1,
               const float* __restrict__ g2, const float* __restrict__ be2,
               float* io) {
  __shared__ float red[4][4];
  const int row = blockIdx.x;
  const int tid = threadIdx.x;
  const int lane = tid & 63, wave = tid >> 6;
  const float* xr = x + (size_t)row * E_;
  float* ior = io + (size_t)row * E_;

  float4 xv = reinterpret_cast<const float4*>(xr)[tid];
  float4 av = reinterpret_cast<const float4*>(ior)[tid];
  float v[4] = {xv.x + av.x, xv.y + av.y, xv.z + av.z, xv.w + av.w};

  float mu1 = block_sum(v[0] + v[1] + v[2] + v[3], red[0], lane, wave) * (1.f / E_);
  float q1 = 0.f;
#pragma unroll
  for (int j = 0; j < 4; ++j) { float d = v[j] - mu1; q1 += d * d; }
  float var1 = block_sum(q1, red[1], lane, wave) * (1.f / E_);
  float rs1 = rsqrtf(var1 + 1e-5f);

  const int e0 = tid * 4;
  float y[4];
#pragma unroll
  for (int j = 0; j < 4; ++j)
    y[j] = (v[j] - mu1) * rs1 * g1[e0 + j] + be1[e0 + j] + ffn_c[e0 + j];

  float mu2 = block_sum(y[0] + y[1] + y[2] + y[3], red[2], lane, wave) * (1.f / E_);
  float q2 = 0.f;
#pragma unroll
  for (int j = 0; j < 4; ++j) { float d = y[j] - mu2; q2 += d * d; }
  float var2 = block_sum(q2, red[3], lane, wave) * (1.f / E_);
  float rs2 = rsqrtf(var2 + 1e-5f);

  float4 o;
  o.x = (y[0] - mu2) * rs2 * g2[e0 + 0] + be2[e0 + 0];
  o.y = (y[1] - mu2) * rs2 * g2[e0 + 1] + be2[e0 + 1];
  o.z = (y[2] - mu2) * rs2 * g2[e0 + 2] + be2[e0 + 2];
  o.w = (y[3] - mu2) * rs2 * g2[e0 + 3] + be2[e0 + 3];
  reinterpret_cast<float4*>(ior)[tid] = o;
}

// ---------------------------------------------------------------------------
extern "C" void kernel_launch(void* const* d_in, const int* in_sizes, int n_in,
                              void* d_out, int out_size, void* d_ws, size_t ws_size,
                              hipStream_t stream) {
  (void)in_sizes; (void)n_in; (void)out_size; (void)ws_size;
  const float* x     = (const float*)d_in[0];
  // d_in[1] = mask (all ones) — unused
  const float* q_out = (const float*)d_in[2];
  const float* w1    = (const float*)d_in[3];
  const float* b1    = (const float*)d_in[4];
  const float* w2    = (const float*)d_in[5];
  const float* b2    = (const float*)d_in[6];
  const float* g1    = (const float*)d_in[7];
  const float* be1   = (const float*)d_in[8];
  const float* g2    = (const float*)d_in[9];
  const float* be2   = (const float*)d_in[10];
  float* out   = (float*)d_out;
  float* ffn_c = (float*)d_ws;   // E_ floats of scratch

  ffn_const_kernel<<<16, 256, 0, stream>>>(q_out, w1, b1, w2, b2, ffn_c);
  dim3 ag(T_ / QBLK, B_ * H_);
  attn_kernel<<<ag, 256, 0, stream>>>(x, out);
  ln_kernel<<<B_ * T_, 256, 0, stream>>>(x, ffn_c, g1, be1, g2, be2, out);
}

// Round 5
// 176.869 us; speedup vs baseline: 2.2981x; 2.2981x over previous
//
#include <hip/hip_runtime.h>

#define E_   1024
#define H_   16
#define DK_  64
#define FFN_ 4096
#define NQ_  8
#define B_   2
#define T_   2048
#define QBLK 64
#define KVBLK 64

#define NPART 256          // split-K chunks for the const-FFN GEMV
#define ROWS_PER_PART (FFN_ / NPART)   // 16

typedef __attribute__((ext_vector_type(8))) __bf16 bf16x8;
typedef __attribute__((ext_vector_type(4))) float f32x4;

__device__ __forceinline__ __bf16 tobf(float f) { return (__bf16)f; }

// ---------------------------------------------------------------------------
// Kernel 1a: split-K partial of ffn_c.  Block p owns rows [p*16, p*16+16) of
// w2; computes h for those rows inline, streams the 64KB slab coalesced,
// writes a 1024-float partial.  grid = 256 x 256 thr.
// ---------------------------------------------------------------------------
__global__ __launch_bounds__(256)
void ffn_part_kernel(const float* __restrict__ q_out, const float* __restrict__ w1,
                     const float* __restrict__ b1, const float* __restrict__ w2,
                     float* __restrict__ part) {
  __shared__ float h[ROWS_PER_PART];
  const int tid = threadIdx.x;
  const int p = blockIdx.x;
  const int f0 = p * ROWS_PER_PART;
  if (tid < ROWS_PER_PART) {
    const int f = f0 + tid;
    float a = b1[f];
#pragma unroll
    for (int n = 0; n < NQ_; ++n) a += q_out[n] * w1[n * FFN_ + f];
    h[tid] = fmaxf(a, 0.f);
  }
  __syncthreads();
  float4 acc = {0.f, 0.f, 0.f, 0.f};
#pragma unroll
  for (int j = 0; j < ROWS_PER_PART; ++j) {
    const float hf = h[j];
    float4 w = reinterpret_cast<const float4*>(w2 + (size_t)(f0 + j) * E_)[tid];
    acc.x += hf * w.x; acc.y += hf * w.y; acc.z += hf * w.z; acc.w += hf * w.w;
  }
  reinterpret_cast<float4*>(part + (size_t)p * E_)[tid] = acc;
}

// Kernel 1b: reduce 256 partials per column + b2.  grid = 4 x 256 thr.
__global__ __launch_bounds__(256)
void ffn_reduce_kernel(const float* __restrict__ part, const float* __restrict__ b2,
                       float* __restrict__ ffn_c) {
  const int e = blockIdx.x * 256 + threadIdx.x;
  float a = b2[e];
  for (int r = 0; r < NPART; ++r) a += part[(size_t)r * E_ + e];
  ffn_c[e] = a;
}

// ---------------------------------------------------------------------------
// Kernel 2: flash attention, q=k=v = head-split x.  bf16 MFMA, f32 softmax.
// grid = (T/QBLK, B*H), 256 thr = 4 waves, wave owns 16 q-rows.
// ---------------------------------------------------------------------------
__global__ __launch_bounds__(256)
void attn_kernel(const float* __restrict__ x, float* __restrict__ out) {
  __shared__ __bf16 Kl[KVBLK][DK_ + 8];       // K-tile row-major [key][d]
  __shared__ __bf16 Vt[DK_][KVBLK + 8];       // V-tile transposed [d][key]
  __shared__ __bf16 Pl[4][16][KVBLK + 8];     // per-wave P tile [qrow][key]

  const int tid  = threadIdx.x;
  const int wave = tid >> 6;
  const int lane = tid & 63;
  const int l16  = lane & 15;
  const int lhi  = lane >> 4;          // 0..3

  const int bh = blockIdx.y;
  const int b  = bh >> 4;              // / H
  const int h  = bh & 15;
  const int qbase = blockIdx.x * QBLK;
  const float* xb = x + (size_t)b * T_ * E_ + h * DK_;   // row stride E_

  // Q fragments for this wave's 16 rows (A-layout: row = l16, k = lhi*8+i)
  bf16x8 qa[2];
  {
    const float* qrow = xb + (size_t)(qbase + wave * 16 + l16) * E_;
#pragma unroll
    for (int kk = 0; kk < 2; ++kk) {
      const float4* p = reinterpret_cast<const float4*>(qrow + kk * 32 + lhi * 8);
      float4 u0 = p[0], u1 = p[1];
      bf16x8 v;
      v[0] = tobf(u0.x); v[1] = tobf(u0.y); v[2] = tobf(u0.z); v[3] = tobf(u0.w);
      v[4] = tobf(u1.x); v[5] = tobf(u1.y); v[6] = tobf(u1.z); v[7] = tobf(u1.w);
      qa[kk] = v;
    }
  }

  f32x4 acc[4];
#pragma unroll
  for (int i = 0; i < 4; ++i) acc[i] = (f32x4){0.f, 0.f, 0.f, 0.f};
  float m_i[4] = {-1e30f, -1e30f, -1e30f, -1e30f};
  float l_i[4] = {0.f, 0.f, 0.f, 0.f};

  const int key = tid >> 2;            // 0..63
  const int d0  = (tid & 3) * 16;      // 0,16,32,48

  for (int t = 0; t < T_ / KVBLK; ++t) {
    __syncthreads();   // all waves done reading K/Vt of previous tile
    // ---- stage K-tile (row-major) and V-tile (transposed) ----
    {
      const float* src = xb + (size_t)(t * KVBLK + key) * E_ + d0;
      const float4* sp = reinterpret_cast<const float4*>(src);
      float4 a0 = sp[0], a1 = sp[1], a2 = sp[2], a3 = sp[3];
      __bf16 tmp[16];
      tmp[0] = tobf(a0.x); tmp[1] = tobf(a0.y); tmp[2] = tobf(a0.z); tmp[3] = tobf(a0.w);
      tmp[4] = tobf(a1.x); tmp[5] = tobf(a1.y); tmp[6] = tobf(a1.z); tmp[7] = tobf(a1.w);
      tmp[8] = tobf(a2.x); tmp[9] = tobf(a2.y); tmp[10] = tobf(a2.z); tmp[11] = tobf(a2.w);
      tmp[12] = tobf(a3.x); tmp[13] = tobf(a3.y); tmp[14] = tobf(a3.z); tmp[15] = tobf(a3.w);
      bf16x8 v0, v1;
#pragma unroll
      for (int j = 0; j < 8; ++j) { v0[j] = tmp[j]; v1[j] = tmp[8 + j]; }
      bf16x8* krow = reinterpret_cast<bf16x8*>(&Kl[key][d0]);
      krow[0] = v0; krow[1] = v1;
#pragma unroll
      for (int j = 0; j < 16; ++j) Vt[d0 + j][key] = tmp[j];
    }
    __syncthreads();

    // ---- S = Q K^T / 8 ----
    f32x4 s[4];
#pragma unroll
    for (int tn = 0; tn < 4; ++tn) {
      bf16x8 kb0 = *reinterpret_cast<const bf16x8*>(&Kl[tn * 16 + l16][lhi * 8]);
      bf16x8 kb1 = *reinterpret_cast<const bf16x8*>(&Kl[tn * 16 + l16][32 + lhi * 8]);
      f32x4 c = (f32x4){0.f, 0.f, 0.f, 0.f};
      c = __builtin_amdgcn_mfma_f32_16x16x32_bf16(qa[0], kb0, c, 0, 0, 0);
      c = __builtin_amdgcn_mfma_f32_16x16x32_bf16(qa[1], kb1, c, 0, 0, 0);
      s[tn] = c * 0.125f;
    }

    // ---- online softmax (rows = lhi*4+i) ----
#pragma unroll
    for (int i = 0; i < 4; ++i) {
      float rm = fmaxf(fmaxf(s[0][i], s[1][i]), fmaxf(s[2][i], s[3][i]));
#pragma unroll
      for (int off = 1; off < 16; off <<= 1) rm = fmaxf(rm, __shfl_xor(rm, off));
      float mn = fmaxf(m_i[i], rm);
      float corr = __expf(m_i[i] - mn);
      m_i[i] = mn;
      float rs = 0.f;
#pragma unroll
      for (int tn = 0; tn < 4; ++tn) {
        float p = __expf(s[tn][i] - mn);
        s[tn][i] = p;
        rs += p;
      }
#pragma unroll
      for (int off = 1; off < 16; off <<= 1) rs += __shfl_xor(rs, off);
      l_i[i] = l_i[i] * corr + rs;
#pragma unroll
      for (int td = 0; td < 4; ++td) acc[td][i] *= corr;
#pragma unroll
      for (int tn = 0; tn < 4; ++tn)
        Pl[wave][lhi * 4 + i][tn * 16 + l16] = tobf(s[tn][i]);
    }
    asm volatile("s_waitcnt lgkmcnt(0)" ::: "memory");  // P writes visible wave-wide

    // ---- O += P V ----
    bf16x8 pa0 = *reinterpret_cast<const bf16x8*>(&Pl[wave][l16][lhi * 8]);
    bf16x8 pa1 = *reinterpret_cast<const bf16x8*>(&Pl[wave][l16][32 + lhi * 8]);
#pragma unroll
    for (int td = 0; td < 4; ++td) {
      bf16x8 vb0 = *reinterpret_cast<const bf16x8*>(&Vt[td * 16 + l16][lhi * 8]);
      bf16x8 vb1 = *reinterpret_cast<const bf16x8*>(&Vt[td * 16 + l16][32 + lhi * 8]);
      acc[td] = __builtin_amdgcn_mfma_f32_16x16x32_bf16(pa0, vb0, acc[td], 0, 0, 0);
      acc[td] = __builtin_amdgcn_mfma_f32_16x16x32_bf16(pa1, vb1, acc[td], 0, 0, 0);
    }
  }

  // ---- epilogue: O / l -> out (attn staged in d_out) ----
#pragma unroll
  for (int td = 0; td < 4; ++td)
#pragma unroll
    for (int i = 0; i < 4; ++i) {
      const int tq  = qbase + wave * 16 + lhi * 4 + i;
      const int col = h * DK_ + td * 16 + l16;
      out[((size_t)b * T_ + tq) * E_ + col] = acc[td][i] / l_i[i];
    }
}

// ---------------------------------------------------------------------------
// Kernel 3: out = LN2( LN1(x + attn) + ffn_c ), in-place on d_out (attn).
// grid = B*T rows, 256 thr, 4 f32/thread.
// ---------------------------------------------------------------------------
__device__ __forceinline__ float block_sum(float v, float* redrow, int lane, int wave) {
#pragma unroll
  for (int off = 1; off < 64; off <<= 1) v += __shfl_xor(v, off);
  if (lane == 0) redrow[wave] = v;
  __syncthreads();
  return redrow[0] + redrow[1] + redrow[2] + redrow[3];
}

__global__ __launch_bounds__(256)
void ln_kernel(const float* __restrict__ x, const float* __restrict__ ffn_c,
               const float* __restrict__ g1, const float* __restrict__ be1,
               const float* __restrict__ g2, const float* __restrict__ be2,
               float* io) {
  __shared__ float red[4][4];
  const int row = blockIdx.x;
  const int tid = threadIdx.x;
  const int lane = tid & 63, wave = tid >> 6;
  const float* xr = x + (size_t)row * E_;
  float* ior = io + (size_t)row * E_;

  float4 xv = reinterpret_cast<const float4*>(xr)[tid];
  float4 av = reinterpret_cast<const float4*>(ior)[tid];
  float v[4] = {xv.x + av.x, xv.y + av.y, xv.z + av.z, xv.w + av.w};

  float mu1 = block_sum(v[0] + v[1] + v[2] + v[3], red[0], lane, wave) * (1.f / E_);
  float q1 = 0.f;
#pragma unroll
  for (int j = 0; j < 4; ++j) { float d = v[j] - mu1; q1 += d * d; }
  float var1 = block_sum(q1, red[1], lane, wave) * (1.f / E_);
  float rs1 = rsqrtf(var1 + 1e-5f);

  const int e0 = tid * 4;
  float y[4];
#pragma unroll
  for (int j = 0; j < 4; ++j)
    y[j] = (v[j] - mu1) * rs1 * g1[e0 + j] + be1[e0 + j] + ffn_c[e0 + j];

  float mu2 = block_sum(y[0] + y[1] + y[2] + y[3], red[2], lane, wave) * (1.f / E_);
  float q2 = 0.f;
#pragma unroll
  for (int j = 0; j < 4; ++j) { float d = y[j] - mu2; q2 += d * d; }
  float var2 = block_sum(q2, red[3], lane, wave) * (1.f / E_);
  float rs2 = rsqrtf(var2 + 1e-5f);

  float4 o;
  o.x = (y[0] - mu2) * rs2 * g2[e0 + 0] + be2[e0 + 0];
  o.y = (y[1] - mu2) * rs2 * g2[e0 + 1] + be2[e0 + 1];
  o.z = (y[2] - mu2) * rs2 * g2[e0 + 2] + be2[e0 + 2];
  o.w = (y[3] - mu2) * rs2 * g2[e0 + 3] + be2[e0 + 3];
  reinterpret_cast<float4*>(ior)[tid] = o;
}

// ---------------------------------------------------------------------------
extern "C" void kernel_launch(void* const* d_in, const int* in_sizes, int n_in,
                              void* d_out, int out_size, void* d_ws, size_t ws_size,
                              hipStream_t stream) {
  (void)in_sizes; (void)n_in; (void)out_size; (void)ws_size;
  const float* x     = (const float*)d_in[0];
  // d_in[1] = mask (all ones) — unused
  const float* q_out = (const float*)d_in[2];
  const float* w1    = (const float*)d_in[3];
  const float* b1    = (const float*)d_in[4];
  const float* w2    = (const float*)d_in[5];
  const float* b2    = (const float*)d_in[6];
  const float* g1    = (const float*)d_in[7];
  const float* be1   = (const float*)d_in[8];
  const float* g2    = (const float*)d_in[9];
  const float* be2   = (const float*)d_in[10];
  float* out   = (float*)d_out;
  float* ffn_c = (float*)d_ws;                  // E_ floats
  float* part  = (float*)d_ws + E_;             // NPART * E_ floats (1 MB)

  ffn_part_kernel<<<NPART, 256, 0, stream>>>(q_out, w1, b1, w2, part);
  ffn_reduce_kernel<<<E_ / 256, 256, 0, stream>>>(part, b2, ffn_c);
  dim3 ag(T_ / QBLK, B_ * H_);
  attn_kernel<<<ag, 256, 0, stream>>>(x, out);
  ln_kernel<<<B_ * T_, 256, 0, stream>>>(x, ffn_c, g1, be1, g2, be2, out);
}

// Round 6
// 152.178 us; speedup vs baseline: 2.6710x; 1.1622x over previous
//
#include <hip/hip_runtime.h>

#define E_   1024
#define H_   16
#define DK_  64
#define FFN_ 4096
#define NQ_  8
#define B_   2
#define T_   2048
#define QBLK 64
#define KVBLK 128
#define NT_  (T_ / KVBLK)

#define NPART 256
#define ROWS_PER_PART (FFN_ / NPART)   // 16

typedef __attribute__((ext_vector_type(8))) __bf16 bf16x8;
typedef __attribute__((ext_vector_type(4))) float f32x4;

__device__ __forceinline__ __bf16 tobf(float f) { return (__bf16)f; }

// ---------------------------------------------------------------------------
// Kernel 1a: split-K partial of ffn_c.
// ---------------------------------------------------------------------------
__global__ __launch_bounds__(256)
void ffn_part_kernel(const float* __restrict__ q_out, const float* __restrict__ w1,
                     const float* __restrict__ b1, const float* __restrict__ w2,
                     float* __restrict__ part) {
  __shared__ float h[ROWS_PER_PART];
  const int tid = threadIdx.x;
  const int p = blockIdx.x;
  const int f0 = p * ROWS_PER_PART;
  if (tid < ROWS_PER_PART) {
    const int f = f0 + tid;
    float a = b1[f];
#pragma unroll
    for (int n = 0; n < NQ_; ++n) a += q_out[n] * w1[n * FFN_ + f];
    h[tid] = fmaxf(a, 0.f);
  }
  __syncthreads();
  float4 acc = {0.f, 0.f, 0.f, 0.f};
#pragma unroll
  for (int j = 0; j < ROWS_PER_PART; ++j) {
    const float hf = h[j];
    float4 w = reinterpret_cast<const float4*>(w2 + (size_t)(f0 + j) * E_)[tid];
    acc.x += hf * w.x; acc.y += hf * w.y; acc.z += hf * w.z; acc.w += hf * w.w;
  }
  reinterpret_cast<float4*>(part + (size_t)p * E_)[tid] = acc;
}

__global__ __launch_bounds__(256)
void ffn_reduce_kernel(const float* __restrict__ part, const float* __restrict__ b2,
                       float* __restrict__ ffn_c) {
  const int e = blockIdx.x * 256 + threadIdx.x;
  float a = b2[e];
  for (int r = 0; r < NPART; ++r) a += part[(size_t)r * E_ + e];
  ffn_c[e] = a;
}

// ---------------------------------------------------------------------------
// Kernel 2: flash attention.  KVBLK=128, register-prefetch pipeline,
// packed-b32 Vt staging.  grid = (T/QBLK, B*H), 256 thr = 4 waves.
// ---------------------------------------------------------------------------
__global__ __launch_bounds__(256)
void attn_kernel(const float* __restrict__ x, float* __restrict__ out) {
  __shared__ __bf16 Kl[KVBLK][DK_ + 8];       // K-tile row-major [key][d]
  __shared__ __bf16 Vt[DK_][KVBLK + 8];       // V-tile transposed [d][key]
  __shared__ __bf16 Pl[4][16][KVBLK + 8];     // per-wave P tile [qrow][key]

  const int tid  = threadIdx.x;
  const int wave = tid >> 6;
  const int lane = tid & 63;
  const int l16  = lane & 15;
  const int lhi  = lane >> 4;          // 0..3

  const int bh = blockIdx.y;
  const int b  = bh >> 4;
  const int h  = bh & 15;
  const int qbase = blockIdx.x * QBLK;
  const float* xb = x + (size_t)b * T_ * E_ + h * DK_;   // row stride E_

  // Q fragments (A-layout: row = l16, k = lhi*8+i)
  bf16x8 qa[2];
  {
    const float* qrow = xb + (size_t)(qbase + wave * 16 + l16) * E_;
#pragma unroll
    for (int kk = 0; kk < 2; ++kk) {
      const float4* p = reinterpret_cast<const float4*>(qrow + kk * 32 + lhi * 8);
      float4 u0 = p[0], u1 = p[1];
      bf16x8 v;
      v[0] = tobf(u0.x); v[1] = tobf(u0.y); v[2] = tobf(u0.z); v[3] = tobf(u0.w);
      v[4] = tobf(u1.x); v[5] = tobf(u1.y); v[6] = tobf(u1.z); v[7] = tobf(u1.w);
      qa[kk] = v;
    }
  }

  f32x4 acc[4];
#pragma unroll
  for (int i = 0; i < 4; ++i) acc[i] = (f32x4){0.f, 0.f, 0.f, 0.f};
  float m_i[4] = {-1e30f, -1e30f, -1e30f, -1e30f};
  float l_i[4] = {0.f, 0.f, 0.f, 0.f};

  // staging assignment: thread owns key-pair (2*kp, 2*kp+1), 16 d-columns
  const int kp = tid >> 2;             // 0..63
  const int d0 = (tid & 3) * 16;       // 0,16,32,48
  const float* kbase = xb + (size_t)(2 * kp) * E_ + d0;

  float4 pr0[4], pr1[4];               // prefetch regs: 2 rows x 16 floats
#pragma unroll
  for (int j = 0; j < 4; ++j) {
    pr0[j] = reinterpret_cast<const float4*>(kbase)[j];
    pr1[j] = reinterpret_cast<const float4*>(kbase + E_)[j];
  }

  for (int t = 0; t < NT_; ++t) {
    __syncthreads();   // all waves done reading previous tile's LDS
    // ---- convert prefetched regs, write K (row-major) + V^T (packed b32) ----
    {
      __bf16 a0[16], a1[16];
#pragma unroll
      for (int j = 0; j < 4; ++j) {
        a0[4*j+0] = tobf(pr0[j].x); a0[4*j+1] = tobf(pr0[j].y);
        a0[4*j+2] = tobf(pr0[j].z); a0[4*j+3] = tobf(pr0[j].w);
        a1[4*j+0] = tobf(pr1[j].x); a1[4*j+1] = tobf(pr1[j].y);
        a1[4*j+2] = tobf(pr1[j].z); a1[4*j+3] = tobf(pr1[j].w);
      }
      bf16x8 v0, v1, w0, w1;
#pragma unroll
      for (int j = 0; j < 8; ++j) {
        v0[j] = a0[j]; v1[j] = a0[8 + j];
        w0[j] = a1[j]; w1[j] = a1[8 + j];
      }
      bf16x8* kr0 = reinterpret_cast<bf16x8*>(&Kl[2 * kp][d0]);
      bf16x8* kr1 = reinterpret_cast<bf16x8*>(&Kl[2 * kp + 1][d0]);
      kr0[0] = v0; kr0[1] = v1;
      kr1[0] = w0; kr1[1] = w1;
#pragma unroll
      for (int j = 0; j < 16; ++j) {
        union { __bf16 hh[2]; unsigned u; } pk;
        pk.hh[0] = a0[j]; pk.hh[1] = a1[j];
        *reinterpret_cast<unsigned*>(&Vt[d0 + j][2 * kp]) = pk.u;
      }
    }
    // ---- issue next tile's global loads (latency hides under compute) ----
    if (t + 1 < NT_) {
      const float* nb = kbase + (size_t)(t + 1) * KVBLK * E_;
#pragma unroll
      for (int j = 0; j < 4; ++j) {
        pr0[j] = reinterpret_cast<const float4*>(nb)[j];
        pr1[j] = reinterpret_cast<const float4*>(nb + E_)[j];
      }
    }
    __syncthreads();

    // ---- S = Q K^T / 8  (8 key-subtiles of 16) ----
    f32x4 s[8];
#pragma unroll
    for (int tn = 0; tn < 8; ++tn) {
      bf16x8 kb0 = *reinterpret_cast<const bf16x8*>(&Kl[tn * 16 + l16][lhi * 8]);
      bf16x8 kb1 = *reinterpret_cast<const bf16x8*>(&Kl[tn * 16 + l16][32 + lhi * 8]);
      f32x4 c = (f32x4){0.f, 0.f, 0.f, 0.f};
      c = __builtin_amdgcn_mfma_f32_16x16x32_bf16(qa[0], kb0, c, 0, 0, 0);
      c = __builtin_amdgcn_mfma_f32_16x16x32_bf16(qa[1], kb1, c, 0, 0, 0);
      s[tn] = c * 0.125f;
    }

    // ---- online softmax (rows = lhi*4+i) ----
#pragma unroll
    for (int i = 0; i < 4; ++i) {
      float rm = s[0][i];
#pragma unroll
      for (int tn = 1; tn < 8; ++tn) rm = fmaxf(rm, s[tn][i]);
#pragma unroll
      for (int off = 1; off < 16; off <<= 1) rm = fmaxf(rm, __shfl_xor(rm, off));
      float mn = fmaxf(m_i[i], rm);
      float corr = __expf(m_i[i] - mn);
      m_i[i] = mn;
      float rs = 0.f;
#pragma unroll
      for (int tn = 0; tn < 8; ++tn) {
        float p = __expf(s[tn][i] - mn);
        s[tn][i] = p;
        rs += p;
      }
#pragma unroll
      for (int off = 1; off < 16; off <<= 1) rs += __shfl_xor(rs, off);
      l_i[i] = l_i[i] * corr + rs;
#pragma unroll
      for (int td = 0; td < 4; ++td) acc[td][i] *= corr;
#pragma unroll
      for (int tn = 0; tn < 8; ++tn)
        Pl[wave][lhi * 4 + i][tn * 16 + l16] = tobf(s[tn][i]);
    }
    asm volatile("s_waitcnt lgkmcnt(0)" ::: "memory");  // P writes visible wave-wide

    // ---- O += P V  (4 key-blocks of 32) ----
#pragma unroll
    for (int kb = 0; kb < 4; ++kb) {
      bf16x8 pa = *reinterpret_cast<const bf16x8*>(&Pl[wave][l16][kb * 32 + lhi * 8]);
#pragma unroll
      for (int td = 0; td < 4; ++td) {
        bf16x8 vb = *reinterpret_cast<const bf16x8*>(&Vt[td * 16 + l16][kb * 32 + lhi * 8]);
        acc[td] = __builtin_amdgcn_mfma_f32_16x16x32_bf16(pa, vb, acc[td], 0, 0, 0);
      }
    }
  }

  // ---- epilogue: O / l -> out (attn staged in d_out) ----
#pragma unroll
  for (int td = 0; td < 4; ++td)
#pragma unroll
    for (int i = 0; i < 4; ++i) {
      const int tq  = qbase + wave * 16 + lhi * 4 + i;
      const int col = h * DK_ + td * 16 + l16;
      out[((size_t)b * T_ + tq) * E_ + col] = acc[td][i] / l_i[i];
    }
}

// ---------------------------------------------------------------------------
// Kernel 3: out = LN2( LN1(x + attn) + ffn_c ), in-place on d_out.
// ---------------------------------------------------------------------------
__device__ __forceinline__ float block_sum(float v, float* redrow, int lane, int wave) {
#pragma unroll
  for (int off = 1; off < 64; off <<= 1) v += __shfl_xor(v, off);
  if (lane == 0) redrow[wave] = v;
  __syncthreads();
  return redrow[0] + redrow[1] + redrow[2] + redrow[3];
}

__global__ __launch_bounds__(256)
void ln_kernel(const float* __restrict__ x, const float* __restrict__ ffn_c,
               const float* __restrict__ g1, const float* __restrict__ be1,
               const float* __restrict__ g2, const float* __restrict__ be2,
               float* io) {
  __shared__ float red[4][4];
  const int row = blockIdx.x;
  const int tid = threadIdx.x;
  const int lane = tid & 63, wave = tid >> 6;
  const float* xr = x + (size_t)row * E_;
  float* ior = io + (size_t)row * E_;

  float4 xv = reinterpret_cast<const float4*>(xr)[tid];
  float4 av = reinterpret_cast<const float4*>(ior)[tid];
  float v[4] = {xv.x + av.x, xv.y + av.y, xv.z + av.z, xv.w + av.w};

  float mu1 = block_sum(v[0] + v[1] + v[2] + v[3], red[0], lane, wave) * (1.f / E_);
  float q1 = 0.f;
#pragma unroll
  for (int j = 0; j < 4; ++j) { float d = v[j] - mu1; q1 += d * d; }
  float var1 = block_sum(q1, red[1], lane, wave) * (1.f / E_);
  float rs1 = rsqrtf(var1 + 1e-5f);

  const int e0 = tid * 4;
  float y[4];
#pragma unroll
  for (int j = 0; j < 4; ++j)
    y[j] = (v[j] - mu1) * rs1 * g1[e0 + j] + be1[e0 + j] + ffn_c[e0 + j];

  float mu2 = block_sum(y[0] + y[1] + y[2] + y[3], red[2], lane, wave) * (1.f / E_);
  float q2 = 0.f;
#pragma unroll
  for (int j = 0; j < 4; ++j) { float d = y[j] - mu2; q2 += d * d; }
  float var2 = block_sum(q2, red[3], lane, wave) * (1.f / E_);
  float rs2 = rsqrtf(var2 + 1e-5f);

  float4 o;
  o.x = (y[0] - mu2) * rs2 * g2[e0 + 0] + be2[e0 + 0];
  o.y = (y[1] - mu2) * rs2 * g2[e0 + 1] + be2[e0 + 1];
  o.z = (y[2] - mu2) * rs2 * g2[e0 + 2] + be2[e0 + 2];
  o.w = (y[3] - mu2) * rs2 * g2[e0 + 3] + be2[e0 + 3];
  reinterpret_cast<float4*>(ior)[tid] = o;
}

// ---------------------------------------------------------------------------
extern "C" void kernel_launch(void* const* d_in, const int* in_sizes, int n_in,
                              void* d_out, int out_size, void* d_ws, size_t ws_size,
                              hipStream_t stream) {
  (void)in_sizes; (void)n_in; (void)out_size; (void)ws_size;
  const float* x     = (const float*)d_in[0];
  const float* q_out = (const float*)d_in[2];
  const float* w1    = (const float*)d_in[3];
  const float* b1    = (const float*)d_in[4];
  const float* w2    = (const float*)d_in[5];
  const float* b2    = (const float*)d_in[6];
  const float* g1    = (const float*)d_in[7];
  const float* be1   = (const float*)d_in[8];
  const float* g2    = (const float*)d_in[9];
  const float* be2   = (const float*)d_in[10];
  float* out   = (float*)d_out;
  float* ffn_c = (float*)d_ws;                  // E_ floats
  float* part  = (float*)d_ws + E_;             // NPART * E_ floats

  ffn_part_kernel<<<NPART, 256, 0, stream>>>(q_out, w1, b1, w2, part);
  ffn_reduce_kernel<<<E_ / 256, 256, 0, stream>>>(part, b2, ffn_c);
  dim3 ag(T_ / QBLK, B_ * H_);
  attn_kernel<<<ag, 256, 0, stream>>>(x, out);
  ln_kernel<<<B_ * T_, 256, 0, stream>>>(x, ffn_c, g1, be1, g2, be2, out);
}